// Round 9
// baseline (431.483 us; speedup 1.0000x reference)
//
#include <hip/hip_runtime.h>

// VectorQuantizer: inputs [65536,128] f32, codebook [1024,128] f32.
// Outputs flat f32: loss(1) | quantized_st(65536*128) | perplexity(1) | encodings(65536*1024)
#define NROWS 65536
#define DIM   128
#define KC    1024
#define QST_OFF  1
#define PPL_OFF  8388609
#define ENC_OFF  8388610

typedef float floatx4 __attribute__((ext_vector_type(4)));
typedef _Float16 half8_t __attribute__((ext_vector_type(8)));
typedef _Float16 half4_t __attribute__((ext_vector_type(4)));

// row stride 144 halfs (288 B): 16B-aligned, 16 spare k-slots (cc fold @128)
#define BSTR 144
#define CIMG 4608             // 32 codes * BSTR: one chunk hi (or lo) image, halfs
#define CCH  9216             // chunk hi+lo image, halfs
#define A_LO 9216             // A-lo image offset in SB (64*BSTR), halfs
#define RPB 64                // rows per block

// --- rounding-exact helpers: numpy-replica fp32 elementwise ops, no contraction ---
__device__ __forceinline__ float fadd_rn_(float a, float b) {
#pragma clang fp contract(off)
  return a + b;
}
__device__ __forceinline__ float fsub_rn_(float a, float b) {
#pragma clang fp contract(off)
  return a - b;
}
__device__ __forceinline__ float fmul_rn_(float a, float b) {
#pragma clang fp contract(off)
  return a * b;
}

// async global->LDS direct copy, 16B per lane (width=16 verified on gfx950)
__device__ __forceinline__ void async_ld16(const void* g, void* l) {
  __builtin_amdgcn_global_load_lds(
      (const __attribute__((address_space(1))) void*)g,
      (__attribute__((address_space(3))) void*)l, 16, 0, 0);
}

// numpy pairwise_sum(x*x) for n=128: 8 accumulators, strided, fixed combine tree.
__device__ __forceinline__ float rowsq128(const float4* src) {
  float r[8];
  {
    float4 v0 = src[0], v1 = src[1];
    r[0] = fmul_rn_(v0.x, v0.x); r[1] = fmul_rn_(v0.y, v0.y);
    r[2] = fmul_rn_(v0.z, v0.z); r[3] = fmul_rn_(v0.w, v0.w);
    r[4] = fmul_rn_(v1.x, v1.x); r[5] = fmul_rn_(v1.y, v1.y);
    r[6] = fmul_rn_(v1.z, v1.z); r[7] = fmul_rn_(v1.w, v1.w);
  }
  for (int i = 1; i < 16; ++i) {
    float4 v0 = src[2 * i], v1 = src[2 * i + 1];
    r[0] = fadd_rn_(r[0], fmul_rn_(v0.x, v0.x));
    r[1] = fadd_rn_(r[1], fmul_rn_(v0.y, v0.y));
    r[2] = fadd_rn_(r[2], fmul_rn_(v0.z, v0.z));
    r[3] = fadd_rn_(r[3], fmul_rn_(v0.w, v0.w));
    r[4] = fadd_rn_(r[4], fmul_rn_(v1.x, v1.x));
    r[5] = fadd_rn_(r[5], fmul_rn_(v1.y, v1.y));
    r[6] = fadd_rn_(r[6], fmul_rn_(v1.z, v1.z));
    r[7] = fadd_rn_(r[7], fmul_rn_(v1.w, v1.w));
  }
  return fadd_rn_(fadd_rn_(fadd_rn_(r[0], r[1]), fadd_rn_(r[2], r[3])),
                  fadd_rn_(fadd_rn_(r[4], r[5]), fadd_rn_(r[6], r[7])));
}

// K_prep R11 (1024 blocks): every block nt-zeroes its 256 KB enc slab (moves
// the 268 MB one-hot zero-fill OUT of k_main's vmcnt-counted loop — infinite
// store slack, explicit HBM-bound phase). Blocks 0-15 additionally do the
// cbT transpose, exact cc chain, and fp16 hi/lo pack (cc fold slot k=128).
// Block 16 zeroes cnt+lsum (replaces the hipMemsetAsync launch).
__global__ __launch_bounds__(256) void k_prep(const float* __restrict__ cb,
                                              float* __restrict__ cbT,
                                              float* __restrict__ cc,
                                              _Float16* __restrict__ Bp,
                                              float* __restrict__ enc,
                                              int* __restrict__ cnti) {
  __shared__ float tile[64 * 129];  // +1 pad: conflict-free transpose
  int t = threadIdx.x;
  int bid = blockIdx.x;

  if (bid < 16) {
    int c0 = bid * 64;
#pragma unroll
    for (int it = 0; it < 32; ++it) {
      int f = it * 256 + t;
      int c = f >> 7, d = f & 127;
      tile[c * 129 + d] = cb[(size_t)(c0 + c) * DIM + d];
    }
    __syncthreads();
#pragma unroll
    for (int it = 0; it < 32; ++it) {
      int f = it * 256 + t;
      int d = f >> 6, c = f & 63;
      cbT[(size_t)d * KC + c0 + c] = tile[c * 129 + d];
    }
    if (t < 64) {
      const float* s = &tile[t * 129];
      float r[8];
#pragma unroll
      for (int j = 0; j < 8; ++j) r[j] = fmul_rn_(s[j], s[j]);
      for (int i = 1; i < 16; ++i) {
#pragma unroll
        for (int j = 0; j < 8; ++j)
          r[j] = fadd_rn_(r[j], fmul_rn_(s[i * 8 + j], s[i * 8 + j]));
      }
      float ccv = fadd_rn_(fadd_rn_(fadd_rn_(r[0], r[1]), fadd_rn_(r[2], r[3])),
                           fadd_rn_(fadd_rn_(r[4], r[5]), fadd_rn_(r[6], r[7])));
      cc[c0 + t] = ccv;
      int g = c0 + t;
      size_t base = (size_t)(g >> 5) * CCH + (size_t)(g & 31) * BSTR;
#pragma unroll
      for (int k = 128; k < 144; ++k) {
        Bp[base + k] = (_Float16)0.0f;
        Bp[base + CIMG + k] = (_Float16)0.0f;
      }
      Bp[base + 128] = (_Float16)(-512.0f * ccv);  // cc fold slot
    }
#pragma unroll
    for (int it = 0; it < 32; ++it) {
      int f = it * 256 + t;
      int c = f >> 7, k = f & 127;
      int g = c0 + c;
      size_t base = (size_t)(g >> 5) * CCH + (size_t)(g & 31) * BSTR;
      float c5 = tile[c * 129 + k] * 512.0f;  // exact pow2 scale
      _Float16 h = (_Float16)c5;
      _Float16 l = (_Float16)(c5 - (float)h);
      Bp[base + k] = h;
      Bp[base + CIMG + k] = l;
    }
  }

  // ---- enc zero slab: 64 rows x 1024 = 256 KB, contiguous nt float4 stores ----
  {
    floatx4 z = {0.f, 0.f, 0.f, 0.f};
    floatx4* e4 = (floatx4*)(enc + (size_t)bid * RPB * KC);
#pragma unroll 4
    for (int i = 0; i < 64; ++i)
      __builtin_nontemporal_store(z, e4 + i * 256 + t);
  }
  if (bid == 16) {  // cnt[1024] + lsum (float 0.0 == 0 bits)
    for (int i = t; i < KC + 1; i += 256) cnti[i] = 0;
  }
}

// K_main R11: 64 rows/block, 1024 blocks, 4/CU, 16 waves/CU. Code-split waves
// (wave w: rows (w>>1)*32..+31 x code-half w&1), cc folded into MFMA, B
// double-buffered via global_load_lds. NO stores in the chunk loop -> the only
// vmem is the DMA, so a plain __syncthreads per chunk is exact (drains DMA c,
// fences buffer reuse). Enc zeros were written by k_prep (kernel ordering).
__global__ __launch_bounds__(256, 4) void k_main(const float* __restrict__ inp,
                                                 const float* __restrict__ cb,
                                                 const float* __restrict__ cbT,
                                                 const _Float16* __restrict__ Bp,
                                                 const float* __restrict__ cc,
                                                 float* __restrict__ out_qst,
                                                 float* __restrict__ out_enc,
                                                 int* __restrict__ cnt,
                                                 float* __restrict__ lsum) {
  __shared__ _Float16 SB[2 * CCH];  // A hi/lo staging image == B double buffer
  __shared__ float xxs[RPB];
  __shared__ int bk[RPB];
  __shared__ int fl_rows[RPB];
  __shared__ int fl_cnt;
  __shared__ float xs[128];
  __shared__ float redd[4];
  __shared__ int redi[4];
  __shared__ float redf[4];
  __shared__ float mb1[RPB][2];
  __shared__ float mb2[RPB][2];
  __shared__ int mi1[RPB][2];

  int t = threadIdx.x;
  int lane = t & 63, w = t >> 6;
  int q = lane >> 4, col = lane & 15;
  int half = w & 1;           // code-half of each chunk
  int wrow = (w >> 1) * 32;   // wave's 32-row base
  int row0 = blockIdx.x * RPB;
  if (t == 0) fl_cnt = 0;

  // ---- stage A as fp16 hi/lo split (64 rows x 32 float4 = 2048 = 8 rounds) ----
  {
    const float* src = inp + (size_t)row0 * DIM;
#pragma unroll
    for (int it = 0; it < 8; ++it) {
      int f = it * 256 + t;
      int r = f >> 5, c4 = f & 31;
      float4 v = *(const float4*)(src + (size_t)r * DIM + c4 * 4);
      _Float16 h0 = (_Float16)v.x, h1 = (_Float16)v.y, h2 = (_Float16)v.z, h3 = (_Float16)v.w;
      half4_t hv = {h0, h1, h2, h3};
      half4_t lv = {(_Float16)(v.x - (float)h0), (_Float16)(v.y - (float)h1),
                    (_Float16)(v.z - (float)h2), (_Float16)(v.w - (float)h3)};
      *(half4_t*)&SB[r * BSTR + c4 * 4] = hv;
      *(half4_t*)&SB[A_LO + r * BSTR + c4 * 4] = lv;
    }
  }
  // exact xx chain, one lane per row (row just fetched -> cache-hot)
  if (t < RPB) xxs[t] = rowsq128((const float4*)(inp + (size_t)(row0 + t) * DIM));
  __syncthreads();

  // ---- A frags -> registers: two 16-row subtiles per wave ----
  int arow0 = wrow + col;
  int arow1 = arow0 + 16;
  half8_t ah0[4], al0[4], ah1[4], al1[4];
#pragma unroll
  for (int ks = 0; ks < 4; ++ks) {
    ah0[ks] = *(const half8_t*)&SB[arow0 * BSTR + ks * 32 + q * 8];
    al0[ks] = *(const half8_t*)&SB[A_LO + arow0 * BSTR + ks * 32 + q * 8];
    ah1[ks] = *(const half8_t*)&SB[arow1 * BSTR + ks * 32 + q * 8];
    al1[ks] = *(const half8_t*)&SB[A_LO + arow1 * BSTR + ks * 32 + q * 8];
  }
  __syncthreads();  // all frag reads done; SB free for B double buffer

  // cc-fold A operand: 0.5 at k-slot 0 (q==0 lanes), zero elsewhere
  half8_t aex = {0, 0, 0, 0, 0, 0, 0, 0};
  if (q == 0) aex[0] = (_Float16)0.5f;

  // max-acc tracking (acc = 512*xc - 256*cc; max acc == min dist). j = s*4+r.
  float b1[8], b2[8];
  int i1[8];
#pragma unroll
  for (int j = 0; j < 8; ++j) { b1[j] = -3.4e38f; b2[j] = -3.4e38f; i1[j] = 0; }

  const float4* bp4 = (const float4*)Bp;  // 1152 float4 / chunk

  // prologue DMA: chunk 0 -> buf0 (1152 float4: 4 full rounds + half round)
  {
    const float4* gsrc = bp4;
#pragma unroll
    for (int r = 0; r < 4; ++r)
      async_ld16(gsrc + r * 256 + t, &SB[(size_t)(r * 256 + t) * 8]);
    if (t < 128) async_ld16(gsrc + 1024 + t, &SB[(size_t)(1024 + t) * 8]);
  }

  for (int c = 0; c < 32; ++c) {
    __syncthreads();  // drains DMA(c) (vmcnt 0); all waves done with prev buf
    if (c < 31) {     // DMA chunk c+1 -> other buffer; retires under compute
      const float4* gsrc = bp4 + (size_t)(c + 1) * 1152;
      int boff = ((c + 1) & 1) * CCH;
#pragma unroll
      for (int r = 0; r < 4; ++r)
        async_ld16(gsrc + r * 256 + t, &SB[boff + (size_t)(r * 256 + t) * 8]);
      if (t < 128) async_ld16(gsrc + 1024 + t, &SB[boff + (size_t)(1024 + t) * 8]);
    }

    const _Float16* Bb = &SB[(c & 1) * CCH];
    floatx4 acc0 = (floatx4){0.f, 0.f, 0.f, 0.f};
    floatx4 acc1 = (floatx4){0.f, 0.f, 0.f, 0.f};
    int brow = half * 16 + col;

#pragma unroll
    for (int ks = 0; ks < 4; ++ks) {
      const _Float16* p = &Bb[brow * BSTR + ks * 32 + q * 8];
      half8_t bh = *(const half8_t*)p;           // hi image
      half8_t bl = *(const half8_t*)(p + CIMG);  // lo image
      acc0 = __builtin_amdgcn_mfma_f32_16x16x32_f16(ah0[ks], bh, acc0, 0, 0, 0);
      acc0 = __builtin_amdgcn_mfma_f32_16x16x32_f16(ah0[ks], bl, acc0, 0, 0, 0);
      acc0 = __builtin_amdgcn_mfma_f32_16x16x32_f16(al0[ks], bh, acc0, 0, 0, 0);
      acc1 = __builtin_amdgcn_mfma_f32_16x16x32_f16(ah1[ks], bh, acc1, 0, 0, 0);
      acc1 = __builtin_amdgcn_mfma_f32_16x16x32_f16(ah1[ks], bl, acc1, 0, 0, 0);
      acc1 = __builtin_amdgcn_mfma_f32_16x16x32_f16(al1[ks], bh, acc1, 0, 0, 0);
    }
    // cc fold: acc += 0.5 * (-512*cc) = -256*cc  (slot 128..135, uniform read)
    {
      half8_t bex = *(const half8_t*)&Bb[brow * BSTR + 128];
      acc0 = __builtin_amdgcn_mfma_f32_16x16x32_f16(aex, bex, acc0, 0, 0, 0);
      acc1 = __builtin_amdgcn_mfma_f32_16x16x32_f16(aex, bex, acc1, 0, 0, 0);
    }

    int kidx = c * 32 + half * 16 + col;
#pragma unroll
    for (int r = 0; r < 4; ++r) {
      {
        float s = acc0[r];
        bool gt = s > b1[r];
        b2[r] = gt ? b1[r] : fmaxf(b2[r], s);
        i1[r] = gt ? kidx : i1[r];
        b1[r] = gt ? s : b1[r];
      }
      {
        float s = acc1[r];
        bool gt = s > b1[4 + r];
        b2[4 + r] = gt ? b1[4 + r] : fmaxf(b2[4 + r], s);
        i1[4 + r] = gt ? kidx : i1[4 + r];
        b1[4 + r] = gt ? s : b1[4 + r];
      }
    }
  }

  // top-2 (max) reduce across the 16 col-lanes; tie -> lower index
#pragma unroll
  for (int j = 0; j < 8; ++j) {
    float v1 = b1[j], v2 = b2[j];
    int ii = i1[j];
    for (int off = 1; off < 16; off <<= 1) {
      float ov1 = __shfl_xor(v1, off);
      float ov2 = __shfl_xor(v2, off);
      int oi = __shfl_xor(ii, off);
      float nb1 = fmaxf(v1, ov1);
      float nb2 = fmaxf(fminf(v1, ov1), fmaxf(v2, ov2));
      ii = (ov1 > v1) ? oi : ((ov1 < v1) ? ii : min(ii, oi));
      v1 = nb1; v2 = nb2;
    }
    b1[j] = v1; b2[j] = v2; i1[j] = ii;
  }

  // per-wave results -> LDS for cross-half merge
  if (col == 0) {
#pragma unroll
    for (int s = 0; s < 2; ++s) {
#pragma unroll
      for (int r = 0; r < 4; ++r) {
        int j = s * 4 + r;
        int row = wrow + s * 16 + q * 4 + r;
        mb1[row][half] = b1[j];
        mb2[row][half] = b2[j];
        mi1[row][half] = i1[j];
      }
    }
  }
  __syncthreads();

  // merge disjoint code-halves per row: exact top-2, min-index ties
  if (t < RPB) {
    float a1 = mb1[t][0], a2 = mb2[t][0];
    int ai = mi1[t][0];
    float c1 = mb1[t][1], c2 = mb2[t][1];
    int ci = mi1[t][1];
    float v1 = fmaxf(a1, c1);
    float v2 = fmaxf(fminf(a1, c1), fmaxf(a2, c2));
    int ii = (c1 > a1) ? ci : ((c1 < a1) ? ai : min(ai, ci));
    bk[t] = ii;
    // dist1 = xx - acc/256; tiered 3-ulp margin in acc units (x256)
    float dist1 = fsub_rn_(xxs[t], fmul_rn_(v1, 0.00390625f));
    float u = (dist1 >= 256.f) ? 9.4e-5f : 4.7e-5f;
    if (v1 - v2 < u * 256.0f) {
      int p = atomicAdd(&fl_cnt, 1);
      fl_rows[p] = t;
    }
  }
  __syncthreads();

  // ---- inline exact fp32 recheck of flagged rows (cbT column scan; rare) ----
  int nf = fl_cnt;
  for (int f = 0; f < nf; ++f) {
    int row = fl_rows[f];
    if (t < 128) xs[t] = inp[(size_t)(row0 + row) * DIM + t];
    __syncthreads();
    float xxr = xxs[row];
    int c0 = t * 4;
    float a0 = 0.f, a1 = 0.f, a2 = 0.f, a3 = 0.f;
    for (int d = 0; d < 128; ++d) {
      float xd = xs[d];
      float4 cv = *(const float4*)&cbT[(size_t)d * KC + c0];
      a0 = __builtin_fmaf(xd, cv.x, a0);
      a1 = __builtin_fmaf(xd, cv.y, a1);
      a2 = __builtin_fmaf(xd, cv.z, a2);
      a3 = __builtin_fmaf(xd, cv.w, a3);
    }
    float aa[4] = {a0, a1, a2, a3};
    float bb = 3.4e38f;
    int bi = 0;
#pragma unroll
    for (int j = 0; j < 4; ++j) {
      float dist = fsub_rn_(fadd_rn_(xxr, cc[c0 + j]), fmul_rn_(2.0f, aa[j]));
      if (dist < bb) { bb = dist; bi = c0 + j; }
    }
    for (int off = 1; off < 64; off <<= 1) {
      float ov = __shfl_xor(bb, off);
      int oi = __shfl_xor(bi, off);
      if (ov < bb || (ov == bb && oi < bi)) { bb = ov; bi = oi; }
    }
    if (lane == 0) { redd[w] = bb; redi[w] = bi; }
    __syncthreads();
    if (t == 0) {
      float vb = redd[0];
      int ib = redi[0];
#pragma unroll
      for (int ww = 1; ww < 4; ++ww) {
        if (redd[ww] < vb || (redd[ww] == vb && redi[ww] < ib)) { vb = redd[ww]; ib = redi[ww]; }
      }
      bk[row] = ib;
    }
    __syncthreads();
  }

  // ---- epilogue: qst + loss + enc ones (zeros pre-written by k_prep) ----
  if (t < RPB) atomicAdd(&cnt[bk[t]], 1);

  float ls = 0.f;
#pragma unroll 4
  for (int it = 0; it < 32; ++it) {
    int f = it * 256 + t;  // 64 rows x 128 d, linear
    int row = f >> 7, d = f & 127;
    size_t gro = (size_t)(row0 + row) * DIM + d;
    float x = inp[gro];
    float qv = cb[(size_t)bk[row] * DIM + d];
    float qe = fsub_rn_(qv, x);
    __builtin_nontemporal_store(fadd_rn_(x, qe), &out_qst[gro]);  // == np: inputs + (quantized - inputs)
    ls = __builtin_fmaf(qe, qe, ls);
  }

  // one 1.0f per row (zeros came from k_prep; kernel ordering guarantees)
  if (t < RPB) out_enc[(size_t)(row0 + t) * KC + bk[t]] = 1.0f;

  // block loss reduce -> one atomic
  for (int off = 32; off; off >>= 1) ls += __shfl_down(ls, off);
  if (lane == 0) redf[w] = ls;
  __syncthreads();
  if (t == 0) atomicAdd(lsum, redf[0] + redf[1] + redf[2] + redf[3]);
}

// K_scalars: loss + perplexity
__global__ __launch_bounds__(1024) void k_scalars(const int* __restrict__ cnt,
                                                  const float* __restrict__ lsum,
                                                  float* __restrict__ out) {
  int t = threadIdx.x;
  float p = (float)cnt[t] * (1.0f / 65536.0f);
  float term = fmul_rn_(p, logf(fadd_rn_(p, 1e-10f)));
  for (int off = 32; off; off >>= 1) term += __shfl_down(term, off);
  __shared__ float red[16];
  if ((t & 63) == 0) red[t >> 6] = term;
  __syncthreads();
  if (t == 0) {
    float s = 0.f;
#pragma unroll
    for (int w = 0; w < 16; ++w) s += red[w];
    out[PPL_OFF] = expf(-s);
    float e = *lsum * (1.0f / 8388608.0f);
    out[0] = fadd_rn_(e, fmul_rn_(0.25f, e));  // q_latent + 0.25*e_latent (equal)
  }
}

extern "C" void kernel_launch(void* const* d_in, const int* in_sizes, int n_in,
                              void* d_out, int out_size, void* d_ws, size_t ws_size,
                              hipStream_t stream) {
  const float* inp = (const float*)d_in[0];
  const float* cb = (const float*)d_in[1];
  float* out = (float*)d_out;

  _Float16* Bp = (_Float16*)d_ws;           // 32 chunks * 9216 halfs = 589824 B
  float* cbT = (float*)(Bp + 32 * CCH);     // 131072 f32
  float* cc = cbT + DIM * KC;               // 1024 f32
  int* cnt = (int*)(cc + KC);               // 1024 i32
  float* lsum = (float*)(cnt + KC);         // 1 f32

  k_prep<<<NROWS / RPB, 256, 0, stream>>>(cb, cbT, cc, Bp, out + ENC_OFF, cnt);
  k_main<<<NROWS / RPB, 256, 0, stream>>>(inp, cb, cbT, Bp, cc,
                                          out + QST_OFF, out + ENC_OFF, cnt, lsum);
  k_scalars<<<1, 1024, 0, stream>>>(cnt, lsum, out);
}

// Round 10
// 388.143 us; speedup vs baseline: 1.1117x; 1.1117x over previous
//
#include <hip/hip_runtime.h>

// VectorQuantizer: inputs [65536,128] f32, codebook [1024,128] f32.
// Outputs flat f32: loss(1) | quantized_st(65536*128) | perplexity(1) | encodings(65536*1024)
#define NROWS 65536
#define DIM   128
#define KC    1024
#define QST_OFF  1
#define PPL_OFF  8388609
#define ENC_OFF  8388610

typedef float floatx4 __attribute__((ext_vector_type(4)));
typedef _Float16 half8_t __attribute__((ext_vector_type(8)));
typedef _Float16 half4_t __attribute__((ext_vector_type(4)));

// row stride 144 halfs (288 B): 16B-aligned, 16 spare k-slots (cc fold @128)
#define BSTR 144
#define CIMG 4608             // 32 codes * BSTR: one chunk hi (or lo) image, halfs
#define CCH  9216             // chunk hi+lo image, halfs
#define A_LO 9216             // A-lo image offset in SB (64*BSTR), halfs
#define RPB 64                // rows per block

// --- rounding-exact helpers: numpy-replica fp32 elementwise ops, no contraction ---
__device__ __forceinline__ float fadd_rn_(float a, float b) {
#pragma clang fp contract(off)
  return a + b;
}
__device__ __forceinline__ float fsub_rn_(float a, float b) {
#pragma clang fp contract(off)
  return a - b;
}
__device__ __forceinline__ float fmul_rn_(float a, float b) {
#pragma clang fp contract(off)
  return a * b;
}

// async global->LDS direct copy, 16B per lane (width=16 verified on gfx950)
__device__ __forceinline__ void async_ld16(const void* g, void* l) {
  __builtin_amdgcn_global_load_lds(
      (const __attribute__((address_space(1))) void*)g,
      (__attribute__((address_space(3))) void*)l, 16, 0, 0);
}

// numpy pairwise_sum(x*x) for n=128: 8 accumulators, strided, fixed combine tree.
__device__ __forceinline__ float rowsq128(const float4* src) {
  float r[8];
  {
    float4 v0 = src[0], v1 = src[1];
    r[0] = fmul_rn_(v0.x, v0.x); r[1] = fmul_rn_(v0.y, v0.y);
    r[2] = fmul_rn_(v0.z, v0.z); r[3] = fmul_rn_(v0.w, v0.w);
    r[4] = fmul_rn_(v1.x, v1.x); r[5] = fmul_rn_(v1.y, v1.y);
    r[6] = fmul_rn_(v1.z, v1.z); r[7] = fmul_rn_(v1.w, v1.w);
  }
  for (int i = 1; i < 16; ++i) {
    float4 v0 = src[2 * i], v1 = src[2 * i + 1];
    r[0] = fadd_rn_(r[0], fmul_rn_(v0.x, v0.x));
    r[1] = fadd_rn_(r[1], fmul_rn_(v0.y, v0.y));
    r[2] = fadd_rn_(r[2], fmul_rn_(v0.z, v0.z));
    r[3] = fadd_rn_(r[3], fmul_rn_(v0.w, v0.w));
    r[4] = fadd_rn_(r[4], fmul_rn_(v1.x, v1.x));
    r[5] = fadd_rn_(r[5], fmul_rn_(v1.y, v1.y));
    r[6] = fadd_rn_(r[6], fmul_rn_(v1.z, v1.z));
    r[7] = fadd_rn_(r[7], fmul_rn_(v1.w, v1.w));
  }
  return fadd_rn_(fadd_rn_(fadd_rn_(r[0], r[1]), fadd_rn_(r[2], r[3])),
                  fadd_rn_(fadd_rn_(r[4], r[5]), fadd_rn_(r[6], r[7])));
}

// K_prep (16 blocks x 64 codes): cbT transpose, exact cc chain, fp16 hi/lo pack
// into 32-code chunk images [hi 4608 | lo 4608]; cc folded at spare slot k=128
// of the hi row as fp16(-512*cc). Block 0 also zeroes cnt+lsum (replaces the
// hipMemsetAsync dispatch; stream order guarantees visibility to k_main).
__global__ __launch_bounds__(256) void k_prep(const float* __restrict__ cb,
                                              float* __restrict__ cbT,
                                              float* __restrict__ cc,
                                              _Float16* __restrict__ Bp,
                                              int* __restrict__ cnti) {
  __shared__ float tile[64 * 129];  // +1 pad: conflict-free transpose
  int t = threadIdx.x;
  int c0 = blockIdx.x * 64;
  if (blockIdx.x == 0) {  // cnt[1024] + lsum (float 0.0 == 0 bits)
    for (int i = t; i < KC + 1; i += 256) cnti[i] = 0;
  }
#pragma unroll
  for (int it = 0; it < 32; ++it) {
    int f = it * 256 + t;
    int c = f >> 7, d = f & 127;
    tile[c * 129 + d] = cb[(size_t)(c0 + c) * DIM + d];
  }
  __syncthreads();
#pragma unroll
  for (int it = 0; it < 32; ++it) {
    int f = it * 256 + t;
    int d = f >> 6, c = f & 63;
    cbT[(size_t)d * KC + c0 + c] = tile[c * 129 + d];
  }
  if (t < 64) {
    const float* s = &tile[t * 129];
    float r[8];
#pragma unroll
    for (int j = 0; j < 8; ++j) r[j] = fmul_rn_(s[j], s[j]);
    for (int i = 1; i < 16; ++i) {
#pragma unroll
      for (int j = 0; j < 8; ++j)
        r[j] = fadd_rn_(r[j], fmul_rn_(s[i * 8 + j], s[i * 8 + j]));
    }
    float ccv = fadd_rn_(fadd_rn_(fadd_rn_(r[0], r[1]), fadd_rn_(r[2], r[3])),
                         fadd_rn_(fadd_rn_(r[4], r[5]), fadd_rn_(r[6], r[7])));
    cc[c0 + t] = ccv;
    int g = c0 + t;
    size_t base = (size_t)(g >> 5) * CCH + (size_t)(g & 31) * BSTR;
#pragma unroll
    for (int k = 128; k < 144; ++k) {
      Bp[base + k] = (_Float16)0.0f;
      Bp[base + CIMG + k] = (_Float16)0.0f;
    }
    Bp[base + 128] = (_Float16)(-512.0f * ccv);  // cc fold slot
  }
#pragma unroll
  for (int it = 0; it < 32; ++it) {
    int f = it * 256 + t;
    int c = f >> 7, k = f & 127;
    int g = c0 + c;
    size_t base = (size_t)(g >> 5) * CCH + (size_t)(g & 31) * BSTR;
    float c5 = tile[c * 129 + k] * 512.0f;  // exact pow2 scale
    _Float16 h = (_Float16)c5;
    _Float16 l = (_Float16)(c5 - (float)h);
    Bp[base + k] = h;
    Bp[base + CIMG + k] = l;
  }
}

// K_main (R8 structure, best measured 389.8 µs total): 64 rows/block, 1024
// blocks, 4/CU, 16 waves/CU. Code-split waves: wave w covers rows (w>>1)*32
// x code-half w&1 — each B ds_read_b128 feeds both row subtiles. Counted-vmcnt
// pipeline: per chunk [vmcnt(2) + s_barrier] -> DMA(c+1) -> 2 enc nt-stores ->
// MFMA; stores stay in flight across barriers, drain at the merge barrier
// (zero-before-one ordering for the enc scatter). cc folded into MFMA.
__global__ __launch_bounds__(256, 4) void k_main(const float* __restrict__ inp,
                                                 const float* __restrict__ cb,
                                                 const float* __restrict__ cbT,
                                                 const _Float16* __restrict__ Bp,
                                                 const float* __restrict__ cc,
                                                 float* __restrict__ out_qst,
                                                 float* __restrict__ out_enc,
                                                 int* __restrict__ cnt,
                                                 float* __restrict__ lsum) {
  __shared__ _Float16 SB[2 * CCH];  // A hi/lo staging image == B double buffer
  __shared__ float xxs[RPB];
  __shared__ int bk[RPB];
  __shared__ int fl_rows[RPB];
  __shared__ int fl_cnt;
  __shared__ float xs[128];
  __shared__ float redd[4];
  __shared__ int redi[4];
  __shared__ float redf[4];
  __shared__ float mb1[RPB][2];
  __shared__ float mb2[RPB][2];
  __shared__ int mi1[RPB][2];

  int t = threadIdx.x;
  int lane = t & 63, w = t >> 6;
  int q = lane >> 4, col = lane & 15;
  int half = w & 1;           // code-half of each chunk
  int wrow = (w >> 1) * 32;   // wave's 32-row base
  int row0 = blockIdx.x * RPB;
  if (t == 0) fl_cnt = 0;

  // ---- stage A as fp16 hi/lo split (64 rows x 32 float4 = 2048 = 8 rounds) ----
  {
    const float* src = inp + (size_t)row0 * DIM;
#pragma unroll
    for (int it = 0; it < 8; ++it) {
      int f = it * 256 + t;
      int r = f >> 5, c4 = f & 31;
      float4 v = *(const float4*)(src + (size_t)r * DIM + c4 * 4);
      _Float16 h0 = (_Float16)v.x, h1 = (_Float16)v.y, h2 = (_Float16)v.z, h3 = (_Float16)v.w;
      half4_t hv = {h0, h1, h2, h3};
      half4_t lv = {(_Float16)(v.x - (float)h0), (_Float16)(v.y - (float)h1),
                    (_Float16)(v.z - (float)h2), (_Float16)(v.w - (float)h3)};
      *(half4_t*)&SB[r * BSTR + c4 * 4] = hv;
      *(half4_t*)&SB[A_LO + r * BSTR + c4 * 4] = lv;
    }
  }
  // exact xx chain, one lane per row (row just fetched -> cache-hot)
  if (t < RPB) xxs[t] = rowsq128((const float4*)(inp + (size_t)(row0 + t) * DIM));
  __syncthreads();

  // ---- A frags -> registers: two 16-row subtiles per wave ----
  int arow0 = wrow + col;
  int arow1 = arow0 + 16;
  half8_t ah0[4], al0[4], ah1[4], al1[4];
#pragma unroll
  for (int ks = 0; ks < 4; ++ks) {
    ah0[ks] = *(const half8_t*)&SB[arow0 * BSTR + ks * 32 + q * 8];
    al0[ks] = *(const half8_t*)&SB[A_LO + arow0 * BSTR + ks * 32 + q * 8];
    ah1[ks] = *(const half8_t*)&SB[arow1 * BSTR + ks * 32 + q * 8];
    al1[ks] = *(const half8_t*)&SB[A_LO + arow1 * BSTR + ks * 32 + q * 8];
  }
  __syncthreads();  // all frag reads done; SB free for B double buffer

  // cc-fold A operand: 0.5 at k-slot 0 (q==0 lanes), zero elsewhere
  half8_t aex = {0, 0, 0, 0, 0, 0, 0, 0};
  if (q == 0) aex[0] = (_Float16)0.5f;

  // max-acc tracking (acc = 512*xc - 256*cc; max acc == min dist). j = s*4+r.
  float b1[8], b2[8];
  int i1[8];
#pragma unroll
  for (int j = 0; j < 8; ++j) { b1[j] = -3.4e38f; b2[j] = -3.4e38f; i1[j] = 0; }

  const float4* bp4 = (const float4*)Bp;                    // 1152 float4 / chunk
  floatx4* enc4 = (floatx4*)(out_enc + (size_t)row0 * KC);  // block's 256KB slab

  // prologue DMA: chunk 0 -> buf0 (1152 float4: 4 full rounds + half round)
  {
    const float4* gsrc = bp4;
#pragma unroll
    for (int r = 0; r < 4; ++r)
      async_ld16(gsrc + r * 256 + t, &SB[(size_t)(r * 256 + t) * 8]);
    if (t < 128) async_ld16(gsrc + 1024 + t, &SB[(size_t)(1024 + t) * 8]);
  }
  asm volatile("s_waitcnt vmcnt(0)" ::: "memory");
  __builtin_amdgcn_sched_barrier(0);
  __builtin_amdgcn_s_barrier();
  __builtin_amdgcn_sched_barrier(0);

  for (int c = 0; c < 32; ++c) {
    if (c > 0) {
      // retire own DMA (chunk c); own 2 enc stores stay in flight
      asm volatile("s_waitcnt vmcnt(2)" ::: "memory");
      __builtin_amdgcn_sched_barrier(0);
      __builtin_amdgcn_s_barrier();
      __builtin_amdgcn_sched_barrier(0);
    }
    if (c < 31) {  // DMA chunk c+1 -> other buffer (oldest vmem of this body)
      const float4* gsrc = bp4 + (size_t)(c + 1) * 1152;
      int boff = ((c + 1) & 1) * CCH;
#pragma unroll
      for (int r = 0; r < 4; ++r)
        async_ld16(gsrc + r * 256 + t, &SB[boff + (size_t)(r * 256 + t) * 8]);
      if (t < 128) async_ld16(gsrc + 1024 + t, &SB[boff + (size_t)(1024 + t) * 8]);
    }
    __builtin_amdgcn_sched_barrier(0);  // pin: DMA strictly before stores
    // enc zero slab for this chunk: rows [2c, 2c+2) full width, 8KB contiguous
    {
      floatx4 z = {0.f, 0.f, 0.f, 0.f};
      __builtin_nontemporal_store(z, enc4 + (size_t)c * 512 + t);
      __builtin_nontemporal_store(z, enc4 + (size_t)c * 512 + 256 + t);
    }
    __builtin_amdgcn_sched_barrier(0);  // pin: stores strictly before compute

    const _Float16* Bb = &SB[(c & 1) * CCH];
    floatx4 acc0 = (floatx4){0.f, 0.f, 0.f, 0.f};
    floatx4 acc1 = (floatx4){0.f, 0.f, 0.f, 0.f};
    int brow = half * 16 + col;

#pragma unroll
    for (int ks = 0; ks < 4; ++ks) {
      const _Float16* p = &Bb[brow * BSTR + ks * 32 + q * 8];
      half8_t bh = *(const half8_t*)p;           // hi image
      half8_t bl = *(const half8_t*)(p + CIMG);  // lo image
      acc0 = __builtin_amdgcn_mfma_f32_16x16x32_f16(ah0[ks], bh, acc0, 0, 0, 0);
      acc0 = __builtin_amdgcn_mfma_f32_16x16x32_f16(ah0[ks], bl, acc0, 0, 0, 0);
      acc0 = __builtin_amdgcn_mfma_f32_16x16x32_f16(al0[ks], bh, acc0, 0, 0, 0);
      acc1 = __builtin_amdgcn_mfma_f32_16x16x32_f16(ah1[ks], bh, acc1, 0, 0, 0);
      acc1 = __builtin_amdgcn_mfma_f32_16x16x32_f16(ah1[ks], bl, acc1, 0, 0, 0);
      acc1 = __builtin_amdgcn_mfma_f32_16x16x32_f16(al1[ks], bh, acc1, 0, 0, 0);
    }
    // cc fold: acc += 0.5 * (-512*cc) = -256*cc  (slot 128..135, uniform read)
    {
      half8_t bex = *(const half8_t*)&Bb[brow * BSTR + 128];
      acc0 = __builtin_amdgcn_mfma_f32_16x16x32_f16(aex, bex, acc0, 0, 0, 0);
      acc1 = __builtin_amdgcn_mfma_f32_16x16x32_f16(aex, bex, acc1, 0, 0, 0);
    }

    int kidx = c * 32 + half * 16 + col;
#pragma unroll
    for (int r = 0; r < 4; ++r) {
      {
        float s = acc0[r];
        bool gt = s > b1[r];
        b2[r] = gt ? b1[r] : fmaxf(b2[r], s);
        i1[r] = gt ? kidx : i1[r];
        b1[r] = gt ? s : b1[r];
      }
      {
        float s = acc1[r];
        bool gt = s > b1[4 + r];
        b2[4 + r] = gt ? b1[4 + r] : fmaxf(b2[4 + r], s);
        i1[4 + r] = gt ? kidx : i1[4 + r];
        b1[4 + r] = gt ? s : b1[4 + r];
      }
    }
  }

  // top-2 (max) reduce across the 16 col-lanes; tie -> lower index
#pragma unroll
  for (int j = 0; j < 8; ++j) {
    float v1 = b1[j], v2 = b2[j];
    int ii = i1[j];
    for (int off = 1; off < 16; off <<= 1) {
      float ov1 = __shfl_xor(v1, off);
      float ov2 = __shfl_xor(v2, off);
      int oi = __shfl_xor(ii, off);
      float nb1 = fmaxf(v1, ov1);
      float nb2 = fmaxf(fminf(v1, ov1), fmaxf(v2, ov2));
      ii = (ov1 > v1) ? oi : ((ov1 < v1) ? ii : min(ii, oi));
      v1 = nb1; v2 = nb2;
    }
    b1[j] = v1; b2[j] = v2; i1[j] = ii;
  }

  // per-wave results -> LDS for cross-half merge
  if (col == 0) {
#pragma unroll
    for (int s = 0; s < 2; ++s) {
#pragma unroll
      for (int r = 0; r < 4; ++r) {
        int j = s * 4 + r;
        int row = wrow + s * 16 + q * 4 + r;
        mb1[row][half] = b1[j];
        mb2[row][half] = b2[j];
        mi1[row][half] = i1[j];
      }
    }
  }
  __syncthreads();  // full drain: enc zeros retired; merge data visible

  // merge disjoint code-halves per row: exact top-2, min-index ties
  if (t < RPB) {
    float a1 = mb1[t][0], a2 = mb2[t][0];
    int ai = mi1[t][0];
    float c1 = mb1[t][1], c2 = mb2[t][1];
    int ci = mi1[t][1];
    float v1 = fmaxf(a1, c1);
    float v2 = fmaxf(fminf(a1, c1), fmaxf(a2, c2));
    int ii = (c1 > a1) ? ci : ((c1 < a1) ? ai : min(ai, ci));
    bk[t] = ii;
    // dist1 = xx - acc/256; tiered 3-ulp margin in acc units (x256)
    float dist1 = fsub_rn_(xxs[t], fmul_rn_(v1, 0.00390625f));
    float u = (dist1 >= 256.f) ? 9.4e-5f : 4.7e-5f;
    if (v1 - v2 < u * 256.0f) {
      int p = atomicAdd(&fl_cnt, 1);
      fl_rows[p] = t;
    }
  }
  __syncthreads();

  // ---- inline exact fp32 recheck of flagged rows (cbT column scan; rare) ----
  int nf = fl_cnt;
  for (int f = 0; f < nf; ++f) {
    int row = fl_rows[f];
    if (t < 128) xs[t] = inp[(size_t)(row0 + row) * DIM + t];
    __syncthreads();
    float xxr = xxs[row];
    int c0 = t * 4;
    float a0 = 0.f, a1 = 0.f, a2 = 0.f, a3 = 0.f;
    for (int d = 0; d < 128; ++d) {
      float xd = xs[d];
      float4 cv = *(const float4*)&cbT[(size_t)d * KC + c0];
      a0 = __builtin_fmaf(xd, cv.x, a0);
      a1 = __builtin_fmaf(xd, cv.y, a1);
      a2 = __builtin_fmaf(xd, cv.z, a2);
      a3 = __builtin_fmaf(xd, cv.w, a3);
    }
    float aa[4] = {a0, a1, a2, a3};
    float bb = 3.4e38f;
    int bi = 0;
#pragma unroll
    for (int j = 0; j < 4; ++j) {
      float dist = fsub_rn_(fadd_rn_(xxr, cc[c0 + j]), fmul_rn_(2.0f, aa[j]));
      if (dist < bb) { bb = dist; bi = c0 + j; }
    }
    for (int off = 1; off < 64; off <<= 1) {
      float ov = __shfl_xor(bb, off);
      int oi = __shfl_xor(bi, off);
      if (ov < bb || (ov == bb && oi < bi)) { bb = ov; bi = oi; }
    }
    if (lane == 0) { redd[w] = bb; redi[w] = bi; }
    __syncthreads();
    if (t == 0) {
      float vb = redd[0];
      int ib = redi[0];
#pragma unroll
      for (int ww = 1; ww < 4; ++ww) {
        if (redd[ww] < vb || (redd[ww] == vb && redi[ww] < ib)) { vb = redd[ww]; ib = redi[ww]; }
      }
      bk[row] = ib;
    }
    __syncthreads();
  }

  // ---- epilogue: qst + loss; enc already zero-filled, just scatter the ones ----
  if (t < RPB) atomicAdd(&cnt[bk[t]], 1);

  float ls = 0.f;
#pragma unroll 4
  for (int it = 0; it < 32; ++it) {
    int f = it * 256 + t;  // 64 rows x 128 d, linear
    int row = f >> 7, d = f & 127;
    size_t gro = (size_t)(row0 + row) * DIM + d;
    float x = inp[gro];
    float qv = cb[(size_t)bk[row] * DIM + d];
    float qe = fsub_rn_(qv, x);
    __builtin_nontemporal_store(fadd_rn_(x, qe), &out_qst[gro]);  // == np: inputs + (quantized - inputs)
    ls = __builtin_fmaf(qe, qe, ls);
  }

  // one 1.0f per row; the zero for this address drained at the merge barrier
  if (t < RPB) out_enc[(size_t)(row0 + t) * KC + bk[t]] = 1.0f;

  // block loss reduce -> one atomic
  for (int off = 32; off; off >>= 1) ls += __shfl_down(ls, off);
  if (lane == 0) redf[w] = ls;
  __syncthreads();
  if (t == 0) atomicAdd(lsum, redf[0] + redf[1] + redf[2] + redf[3]);
}

// K_scalars: loss + perplexity
__global__ __launch_bounds__(1024) void k_scalars(const int* __restrict__ cnt,
                                                  const float* __restrict__ lsum,
                                                  float* __restrict__ out) {
  int t = threadIdx.x;
  float p = (float)cnt[t] * (1.0f / 65536.0f);
  float term = fmul_rn_(p, logf(fadd_rn_(p, 1e-10f)));
  for (int off = 32; off; off >>= 1) term += __shfl_down(term, off);
  __shared__ float red[16];
  if ((t & 63) == 0) red[t >> 6] = term;
  __syncthreads();
  if (t == 0) {
    float s = 0.f;
#pragma unroll
    for (int w = 0; w < 16; ++w) s += red[w];
    out[PPL_OFF] = expf(-s);
    float e = *lsum * (1.0f / 8388608.0f);
    out[0] = fadd_rn_(e, fmul_rn_(0.25f, e));  // q_latent + 0.25*e_latent (equal)
  }
}

extern "C" void kernel_launch(void* const* d_in, const int* in_sizes, int n_in,
                              void* d_out, int out_size, void* d_ws, size_t ws_size,
                              hipStream_t stream) {
  const float* inp = (const float*)d_in[0];
  const float* cb = (const float*)d_in[1];
  float* out = (float*)d_out;

  _Float16* Bp = (_Float16*)d_ws;           // 32 chunks * 9216 halfs = 589824 B
  float* cbT = (float*)(Bp + 32 * CCH);     // 131072 f32
  float* cc = cbT + DIM * KC;               // 1024 f32
  int* cnt = (int*)(cc + KC);               // 1024 i32
  float* lsum = (float*)(cnt + KC);         // 1 f32

  k_prep<<<KC / 64, 256, 0, stream>>>(cb, cbT, cc, Bp, cnt);
  k_main<<<NROWS / RPB, 256, 0, stream>>>(inp, cb, cbT, Bp, cc,
                                          out + QST_OFF, out + ENC_OFF, cnt, lsum);
  k_scalars<<<1, 1024, 0, stream>>>(cnt, lsum, out);
}